// Round 2
// baseline (729.662 us; speedup 1.0000x reference)
//
#include <hip/hip_runtime.h>
#include <hip/hip_bf16.h>
#include <math.h>

#define HW 16384

__device__ __forceinline__ float LD(const void* p, long i, int bf){
  return bf ? __bfloat162float(((const __hip_bfloat16*)p)[i]) : ((const float*)p)[i];
}
__device__ __forceinline__ float geluf(float x){ return 0.5f*x*(1.0f + erff(x*0.70710678118654752f)); }

// ---- ws layout (float offsets) ----
#define OFF_M    0            // Mq(1024) Mk(1024) Mv(1024)
#define OFF_G    3072         // 4 batches * 3 mats * 256 -> [3072,3840) used, zero to 6144
#define OFF_MB   6144         // 4 * 16*64
#define OFF_FLAG 10240        // int flag: 1 = inputs are bf16, 0 = fp32
#define OFF_QDIM 16384
#define OFF_KDIM (16384 + 1048576)
#define OFF_VDIM (16384 + 2*1048576)
#define OFF_QMIX (16384 + 3*1048576)
#define OFF_KMIX (16384 + 4*1048576)
#define OFF_VMIX (16384 + 5*1048576)
#define OFF_S    (16384 + 6*1048576)
#define FSZ 532480            // 4*16*128*65
// wavelet scratch reuses dead regions:
//   Y64 -> OFF_QDIM (1M), N48 -> OFF_KDIM (768K),
//   M96 -> OFF_S (1.5M), G96 -> OFF_S+1572864 (1.5M)
// total ws requirement: (OFF_S + 3145728) * 4 bytes = 37.8 MB

// K-1: dtype flag + zero atomic accumulators
__global__ void k_flag(const void* bng, float* ws){
  int t=threadIdx.x;
  for(int i=3072+t;i<10240;i+=256) ws[i]=0.f;
  if(t==0){
    float v = ((const float*)bng)[0];        // safe: buffer >= 96 bytes in either dtype
    ((int*)ws)[OFF_FLAG] = (v==1.0f) ? 0 : 1;
  }
}

// K0: Mq/Mk/Mv = W{q,k,v} @ Wr   [64,512]@[512,16] -> [64,16]
__global__ void k_fold(const void* Wq, const void* Wk, const void* Wv,
                       const void* Wr, float* ws, const int* flg){
  int bf=*flg;
  const void* Wsrc = blockIdx.x==0 ? Wq : (blockIdx.x==1 ? Wk : Wv);
  float* dst = ws + blockIdx.x*1024;
  __shared__ float wr[512*16];
  for(int i=threadIdx.x;i<8192;i+=256) wr[i]=LD(Wr,i,bf);
  __syncthreads();
  for(int o=threadIdx.x;o<1024;o+=256){
    int c=o>>4, r=o&15; float acc=0.f;
    for(int j=0;j<512;j++) acc += LD(Wsrc,(long)c*512+j,bf)*wr[j*16+r];
    dst[o]=acc;
  }
}

// K1: q/k/v_dim[b,n,r] = x[b,n,:] @ M{q,k,v}
__global__ void k_dims(const void* x, const float* ws,
                       float* qd, float* kd, float* vd, const int* flg){
  int bf=*flg;
  __shared__ float xs[16*64];
  __shared__ float ms[3*1024];
  int b = blockIdx.x>>10;
  int pix0 = (blockIdx.x & 1023)<<4;
  int t = threadIdx.x;
  for(int i=t;i<3072;i+=256) ms[i]=ws[i];
  long base = ((long)b*HW + pix0)*64;
  for(int i=t;i<1024;i+=256) xs[i]=LD(x, base+i, bf);
  __syncthreads();
  int p=t>>4, r=t&15;
  float aq=0.f,ak=0.f,av=0.f;
  for(int c=0;c<64;c++){
    float xv = xs[p*64+c];
    aq += xv*ms[c*16+r];
    ak += xv*ms[1024+c*16+r];
    av += xv*ms[2048+c*16+r];
  }
  long o = ((long)b*HW + pix0)*16 + t;
  qd[o]=aq; kd[o]=ak; vd[o]=av;
}

// K2: SpitialUnit: q_mix = q_dim + gamma * pw(gelu(dw3x3(q_dim)))
__global__ void k_spatial(const float* qd, float* qm, const void* dw,
                          const void* pw, const void* gamma, const int* flg){
  int bf=*flg;
  __shared__ float tile[3*128*16];
  __shared__ float dws[144], pws[256], gs[16];
  int b = blockIdx.x>>7, y = blockIdx.x&127;
  int t = threadIdx.x; // 128
  for(int i=t;i<144;i+=128) dws[i]=LD(dw,i,bf);
  for(int i=t;i<256;i+=128) pws[i]=LD(pw,i,bf);
  if(t<16) gs[t]=LD(gamma,t,bf);
  for(int i=t;i<6144;i+=128){
    int ry = i/2048, rem = i%2048;
    int yy = y-1+ry;
    tile[i] = (yy>=0 && yy<128) ? qd[(long)(b*128+yy)*2048 + rem] : 0.f;
  }
  __syncthreads();
  int x=t;
  float g[16];
  for(int ch=0;ch<16;ch++){
    float acc=0.f;
    for(int p=0;p<3;p++)
      for(int q=0;q<3;q++){
        int xx=x-1+q;
        if(xx>=0&&xx<128) acc += dws[ch*9+p*3+q]*tile[(p*128+xx)*16+ch];
      }
    g[ch]=geluf(acc);
  }
  long ob = ((long)(b*128+y)*128 + x)*16;
  for(int c=0;c<16;c++){
    float acc=0.f;
    for(int ch=0;ch<16;ch++) acc += pws[c*16+ch]*g[ch];
    qm[ob+c] = tile[(128+x)*16+c] + gs[c]*acc;
  }
}

#define MAKE_TWIDDLE(ct,st) { int tt=threadIdx.x; if(tt<128){ float ang = 6.283185307179586f*(float)tt/128.f; float s_,c_; sincosf(ang,&s_,&c_); ct[tt]=c_; st[tt]=s_; } }

// F1: per (b,c,y) row rfft over x -> R[bc, v, y]
__global__ void k_fft_row(const float* kd, float* Rre, float* Rim){
  __shared__ float row[128], ct[128], st[128];
  int blk=blockIdx.x; int y=blk&127; int bc=blk>>7;
  int b=bc>>4, c=bc&15;
  int t=threadIdx.x;
  MAKE_TWIDDLE(ct,st);
  row[t] = kd[((long)(b*128+y)*128+t)*16+c];
  __syncthreads();
  if(t<65){
    float re=0.f, im=0.f;
    for(int x=0;x<128;x++){
      float v=row[x]; int idx=(t*x)&127;
      re += v*ct[idx]; im -= v*st[idx];
    }
    long o = ((long)bc*65+t)*128 + y;
    Rre[o]=re; Rim[o]=im;
  }
}

// F2: per (b,c,v) full fft over y, scale 1/128 (ortho fwd), emit amp/phase [b,c,u,v]
__global__ void k_fft_col(const float* Rre, const float* Rim, float* amp, float* ph){
  __shared__ float rre[128], rim[128], ct[128], st[128];
  int blk=blockIdx.x; int v=blk%65; int bc=blk/65;
  int t=threadIdx.x;
  MAKE_TWIDDLE(ct,st);
  long ib = ((long)bc*65+v)*128;
  rre[t]=Rre[ib+t]; rim[t]=Rim[ib+t];
  __syncthreads();
  float re=0.f, im=0.f;
  for(int y=0;y<128;y++){
    int idx=(t*y)&127;
    float c_=ct[idx], s_=st[idx];
    re += rre[y]*c_ + rim[y]*s_;
    im += rim[y]*c_ - rre[y]*s_;
  }
  re *= (1.f/128.f); im *= (1.f/128.f);
  long o = ((long)bc*128+t)*65+v;
  amp[o]=sqrtf(re*re+im*im);
  ph[o]=atan2f(im,re);
}

// F3: per (b,u,v) pixel: masked amp pointwise + gelu (lo/hi), phase pointwise
__global__ void k_four_pw(const float* amp, const float* ph, float* glo, float* ghi, float* pho,
                          const void* alpw, const void* ahpw,
                          const void* phpw, const void* phs, const int* flg){
  int bf=*flg;
  __shared__ float wl[256], wh[256], wp[256];
  int t=threadIdx.x;
  wl[t]=LD(alpw,t,bf); wh[t]=LD(ahpw,t,bf); wp[t]=LD(phpw,t,bf);
  __syncthreads();
  int p = blockIdx.x*256+t; // 33280 exact
  int b = p/8320; int rem=p%8320; int u=rem/65; int v=rem%65;
  float yy=(float)u/127.f, xx=(float)v/64.f;
  float rr=sqrtf(yy*yy+xx*xx);
  float lo = 1.f/(1.f+expf((rr-0.25f)*20.f));
  float hi = 1.f-lo;
  float alv[16], ahv[16], pv[16];
  for(int ch=0;ch<16;ch++){
    long idx=((long)(b*16+ch)*128+u)*65+v;
    float a=amp[idx];
    alv[ch]=a*lo; ahv[ch]=a*hi; pv[ch]=ph[idx];
  }
  float pscale = LD(phs,0,bf);
  for(int c=0;c<16;c++){
    float al=0.f, ah=0.f, pp=0.f;
    for(int ch=0;ch<16;ch++){
      al += wl[c*16+ch]*alv[ch];
      ah += wh[c*16+ch]*ahv[ch];
      pp += wp[c*16+ch]*pv[ch];
    }
    long o=((long)(b*16+c)*128+u)*65+v;
    glo[o]=geluf(al); ghi[o]=geluf(ah); pho[o]=pv[c]+pscale*pp;
  }
}

// F4: depthwise 3x3 on lo/hi branches, Y = amp_out * e^{i phase_out}, layout [b,c,v,u]
__global__ void k_four_dw(const float* glo, const float* ghi, const float* pho,
                          float* Yre, float* Yim,
                          const void* aldw, const void* ahdw, const int* flg){
  int bf=*flg;
  __shared__ float wl[144], wh[144];
  int t=threadIdx.x;
  if(t<144){wl[t]=LD(aldw,t,bf); wh[t]=LD(ahdw,t,bf);}
  __syncthreads();
  long p = (long)blockIdx.x*256+t;  // 532480 exact
  int v = (int)(p%65); long r1=p/65; int u=(int)(r1%128); int bc=(int)(r1/128); int c=bc&15;
  float acc=0.f;
  for(int dp=0;dp<3;dp++){
    int uu=u-1+dp; if(uu<0||uu>=128) continue;
    for(int dq=0;dq<3;dq++){
      int vv=v-1+dq; if(vv<0||vv>=65) continue;
      long idx=((long)bc*128+uu)*65+vv;
      acc += wl[c*9+dp*3+dq]*glo[idx] + wh[c*9+dp*3+dq]*ghi[idx];
    }
  }
  float pvv = pho[((long)bc*128+u)*65+v];
  float s_,c_; sincosf(pvv,&s_,&c_);
  long o = ((long)bc*65+v)*128+u;
  Yre[o]=acc*c_; Yim[o]=acc*s_;
}

// I1: per (b,c,v): inverse fft over u (e^{+i}), unscaled; Z layout [b,c,y,v]
__global__ void k_ifft_col(const float* Yre, const float* Yim, float* Zre, float* Zim){
  __shared__ float yre[128], yim[128], ct[128], st[128];
  int blk=blockIdx.x; int v=blk%65; int bc=blk/65;
  int t=threadIdx.x;
  MAKE_TWIDDLE(ct,st);
  long ib=((long)bc*65+v)*128;
  yre[t]=Yre[ib+t]; yim[t]=Yim[ib+t];
  __syncthreads();
  float re=0.f,im=0.f;
  for(int u=0;u<128;u++){
    int idx=(t*u)&127; float c_=ct[idx], s_=st[idx];
    re += yre[u]*c_ - yim[u]*s_;
    im += yim[u]*c_ + yre[u]*s_;
  }
  long o=((long)bc*128+t)*65+v;
  Zre[o]=re; Zim[o]=im;
}

// I2: per (b,c,y): hermitian irfft over v (65->128), total scale 1/128, write k_mix NHWC
__global__ void k_ifft_row(const float* Zre, const float* Zim, float* km){
  __shared__ float zre[65], zim[65], ct[128], st[128];
  int blk=blockIdx.x; int y=blk&127; int bc=blk>>7; int b=bc>>4, c=bc&15;
  int t=threadIdx.x;
  MAKE_TWIDDLE(ct,st);
  long ib=((long)bc*128+y)*65;
  if(t<65){ zre[t]=Zre[ib+t]; zim[t]=Zim[ib+t]; }
  __syncthreads();
  int j=t;
  float acc = zre[0] + ((j&1)? -zre[64] : zre[64]);
  for(int k=1;k<64;k++){
    int idx=(j*k)&127;
    acc += 2.f*(zre[k]*ct[idx] - zim[k]*st[idx]);
  }
  acc *= (1.f/128.f);
  km[((long)(b*128+y)*128+j)*16+c]=acc;
}

// W1: Haar stride-2 (torch repeat/chunk layout) + BN on the 48 high channels
__global__ void k_haar(const float* vd, float* y64, float* n48,
                       const void* bng, const void* bnb, const int* flg){
  int bf=*flg;
  __shared__ float gs[48], bs[48];
  int t=threadIdx.x;
  if(t<48){ gs[t]=LD(bng,t,bf)*(1.f/sqrtf(1.f+1e-5f)); bs[t]=LD(bnb,t,bf); }
  __syncthreads();
  int p=blockIdx.x*256+t; // 16384 exact
  int b=p>>12; int ij=p&4095; int i=ij>>6; int j=ij&63;
  long base = (long)b*HW*16;
  long r0=base + ((long)(2*i)*128+2*j)*16, r1=r0+16;
  long r2=base + ((long)(2*i+1)*128+2*j)*16, r3=r2+16;
  long ob=(long)b*64*4096 + ij;
  for(int c=0;c<16;c++){
    float a=vd[r0+c], bb=vd[r1+c], cc=vd[r2+c], dd=vd[r3+c];
    float f[4];
    f[0]=(a+bb+cc+dd)*0.5f; f[1]=(a-bb+cc-dd)*0.5f;
    f[2]=(a+bb-cc-dd)*0.5f; f[3]=(a-bb-cc+dd)*0.5f;
    for(int ff=0;ff<4;ff++){
      int m=4*c+ff;
      y64[ob + (long)m*4096]=f[ff];
      if(m>=16){ int cc2=m-16; n48[((long)b*48+cc2)*4096+ij]=f[ff]*gs[cc2]+bs[cc2]; }
    }
  }
}

// W2: 1x1 conv 48->96
__global__ void k_wmlp_in(const float* n48, float* m96, const void* win, const int* flg){
  int bf=*flg;
  __shared__ float w[48];
  int t=threadIdx.x;
  long gid=(long)blockIdx.x*256+t;
  int ij=(int)(gid&4095); long r=gid>>12; int c=(int)(r%96); int b=(int)(r/96);
  if(t<48) w[t]=LD(win, (long)c*48+t, bf);
  __syncthreads();
  float acc=0.f;
  long nb=(long)b*48*4096 + ij;
  for(int cc=0;cc<48;cc++) acc += w[cc]*n48[nb + (long)cc*4096];
  m96[gid]=acc;
}

// W3: depthwise 3x3 (96ch) + gelu
__global__ void k_wmlp_dw(const float* m96, float* g96, const void* wdw, const int* flg){
  int bf=*flg;
  __shared__ float w[9];
  int t=threadIdx.x;
  long gid=(long)blockIdx.x*256+t;
  int ij=(int)(gid&4095); long r=gid>>12; int c=(int)(r%96);
  if(t<9) w[t]=LD(wdw, (long)c*9+t, bf);
  __syncthreads();
  int i=ij>>6, j=ij&63;
  long pb = gid - ij;
  float acc=0.f;
  for(int dp=0;dp<3;dp++){ int ii=i-1+dp; if(ii<0||ii>=64) continue;
    for(int dq=0;dq<3;dq++){ int jj=j-1+dq; if(jj<0||jj>=64) continue;
      acc += w[dp*3+dq]*m96[pb + ii*64+jj]; } }
  g96[gid]=geluf(acc);
}

// W4: 1x1 conv 96->48, residual, inverse wavelet interleave into v_mix NHWC
__global__ void k_wmlp_out(const float* g96, const float* y64, float* vm,
                           const void* wout, const void* rs, const int* flg){
  int bf=*flg;
  __shared__ float w[96];
  int t=threadIdx.x;
  long gid=(long)blockIdx.x*256+t;
  int ij=(int)(gid&4095); long r=gid>>12; int cc=(int)(r%48); int b=(int)(r/48);
  if(t<96) w[t]=LD(wout, (long)cc*96+t, bf);
  __syncthreads();
  float acc=0.f;
  long gb=(long)b*96*4096+ij;
  for(int c=0;c<96;c++) acc += w[c]*g96[gb+(long)c*4096];
  float he = y64[((long)b*64+16+cc)*4096+ij] + LD(rs,0,bf)*acc;
  int i=ij>>6, j=ij&63;
  int f=cc>>4, c16=cc&15;
  int pp = (f==0)?0:1; int qq=(f==1)?0:1;
  vm[((long)(b*128 + 2*i+pp)*128 + (2*j+qq))*16 + c16] = he;
  if(cc<16){
    vm[((long)(b*128+2*i)*128 + 2*j)*16 + cc] = y64[((long)b*64+cc)*4096+ij];
  }
}

// A1: per-batch Gram matrices Gkq, Gkk, Gqq [16,16]
__global__ void k_gram(const float* qm, const float* km, float* G){
  __shared__ float qs[256*16], ks[256*16];
  int b=blockIdx.x>>3; int chunk=blockIdx.x&7;
  int t=threadIdx.x; int r=t>>4, s=t&15;
  float akq=0.f, akk=0.f, aqq=0.f;
  for(int tile=0;tile<8;tile++){
    long pb=((long)b*HW + chunk*2048 + tile*256)*16;
    for(int i=t;i<4096;i+=256){ qs[i]=qm[pb+i]; ks[i]=km[pb+i]; }
    __syncthreads();
    for(int p=0;p<256;p++){
      float kv=ks[p*16+r], qv=qs[p*16+s];
      akq += kv*qv;
      akk += kv*ks[p*16+s];
      aqq += qs[p*16+r]*qv;
    }
    __syncthreads();
  }
  float* Gb=G + b*768;
  atomicAdd(&Gb[t], akq);
  atomicAdd(&Gb[256+t], akk);
  atomicAdd(&Gb[512+t], aqq);
}

// A2: per (b,h): attn from Gram, softmax, fold into M_b[16,64]
__global__ void k_attn(const float* G, float* Mb, const void* We,
                       const void* Wproj, const void* resc, const int* flg){
  int bf=*flg;
  __shared__ float wes[16*64];     // [r][e]
  __shared__ float gkq[256], gkk[256], gqq[256];
  __shared__ float ukq[64*16], ukk[64*16], uqq[64*16];
  __shared__ float nk[64], nq[64];
  __shared__ float A[64*64];
  __shared__ float T[64*16];
  __shared__ float wpj[64*64];     // [d][c]
  int b=blockIdx.x>>3, h=blockIdx.x&7;
  int t=threadIdx.x;
  for(int i=t;i<1024;i+=256){ int rr=i>>6, e=i&63; wes[rr*64+e]=LD(We, (long)rr*512 + h*64 + e, bf); }
  gkq[t]=G[b*768+t]; gkk[t]=G[b*768+256+t]; gqq[t]=G[b*768+512+t];
  for(int i=t;i<4096;i+=256){ int d=i>>6, c=i&63; wpj[i]=LD(Wproj,(long)(h*64+d)*64+c,bf); }
  __syncthreads();
  for(int i=t;i<1024;i+=256){
    int d=i>>4, s=i&15;
    float a1=0.f,a2=0.f,a3=0.f;
    for(int rr=0;rr<16;rr++){ float wv=wes[rr*64+d]; a1+=wv*gkq[rr*16+s]; a2+=wv*gkk[rr*16+s]; a3+=wv*gqq[rr*16+s]; }
    ukq[i]=a1; ukk[i]=a2; uqq[i]=a3;
  }
  __syncthreads();
  if(t<64){ float a=0.f; for(int s=0;s<16;s++) a+=ukk[t*16+s]*wes[s*64+t]; nk[t]=fmaxf(sqrtf(a),1e-12f); }
  else if(t<128){ int e=t-64; float a=0.f; for(int s=0;s<16;s++) a+=uqq[e*16+s]*wes[s*64+e]; nq[e]=fmaxf(sqrtf(a),1e-12f); }
  __syncthreads();
  float rsc=LD(resc,h,bf);
  for(int i=t;i<4096;i+=256){
    int d=i>>6, e=i&63;
    float a=0.f; for(int s=0;s<16;s++) a+=ukq[d*16+s]*wes[s*64+e];
    A[i]=a/(nk[d]*nq[e])*rsc;
  }
  __syncthreads();
  if(t<64){
    int d=t; float m=-1e30f;
    for(int e=0;e<64;e++) m=fmaxf(m,A[d*64+e]);
    float sum=0.f;
    for(int e=0;e<64;e++){ float ev=expf(A[d*64+e]-m); A[d*64+e]=ev; sum+=ev; }
    float inv=1.f/sum;
    for(int e=0;e<64;e++) A[d*64+e]*=inv;
  }
  __syncthreads();
  for(int i=t;i<1024;i+=256){
    int d=i>>4, s=i&15;
    float a=0.f; for(int e=0;e<64;e++) a+=A[d*64+e]*wes[s*64+e];
    T[i]=a;
  }
  __syncthreads();
  for(int i=t;i<1024;i+=256){
    int s=i>>6, c=i&63;
    float a=0.f; for(int d=0;d<64;d++) a+=T[d*16+s]*wpj[d*64+c];
    atomicAdd(&Mb[b*1024 + s*64 + c], a);
  }
}

// A3: out[b,n,c] = v_mix[b,n,:] @ M_b[:,c] + bproj[c]
__global__ void k_out(const float* vm, const float* Mb, const void* bproj,
                      void* out, const int* flg){
  int bf=*flg;
  long o=(long)blockIdx.x*256+threadIdx.x;
  int c=(int)(o&63); long r=o>>6; int n=(int)(r&16383); int b=(int)(r>>14);
  const float* v=vm + ((long)b*HW+n)*16;
  const float* M=Mb + b*1024;
  float acc=LD(bproj,c,bf);
  for(int s=0;s<16;s++) acc += v[s]*M[s*64+c];
  if(bf) ((__hip_bfloat16*)out)[o]=__float2bfloat16(acc);
  else   ((float*)out)[o]=acc;
}

extern "C" void kernel_launch(void* const* d_in, const int* in_sizes, int n_in,
                              void* d_out, int out_size, void* d_ws, size_t ws_size,
                              hipStream_t stream) {
  const void* x_in   = d_in[0];
  const void* Wq     = d_in[1];
  const void* Wk     = d_in[2];
  const void* Wv     = d_in[3];
  const void* Wr     = d_in[4];
  const void* We     = d_in[5];
  const void* qs_dw  = d_in[6];
  const void* qs_pw  = d_in[7];
  const void* qs_g   = d_in[8];
  const void* al_pw  = d_in[9];
  const void* al_dw  = d_in[10];
  const void* ah_pw  = d_in[11];
  const void* ah_dw  = d_in[12];
  const void* ph_pw  = d_in[13];
  const void* ph_s   = d_in[14];
  const void* bn_g   = d_in[15];
  const void* bn_b   = d_in[16];
  const void* mlp_in = d_in[17];
  const void* mlp_dw = d_in[18];
  const void* mlp_out= d_in[19];
  const void* res_s  = d_in[20];
  const void* rescale= d_in[21];
  const void* Wproj  = d_in[22];
  const void* bproj  = d_in[23];
  float* ws = (float*)d_ws;
  const int* flg = ((const int*)ws) + OFF_FLAG;

  float* FA = ws + OFF_S;
  float* FB = FA + FSZ;
  float* FC = FB + FSZ;
  float* FD = FC + FSZ;
  float* FE = FD + FSZ;
  // wavelet scratch reuses dead regions (q_dim/k_dim/FFT bufs dead by then)
  float* Y64 = ws + OFF_QDIM;
  float* N48 = ws + OFF_KDIM;
  float* M96 = ws + OFF_S;
  float* G96 = ws + OFF_S + 1572864;

  k_flag<<<1,256,0,stream>>>(bn_g, ws);
  k_fold<<<3,256,0,stream>>>(Wq,Wk,Wv,Wr, ws, flg);
  k_dims<<<4096,256,0,stream>>>(x_in, ws, ws+OFF_QDIM, ws+OFF_KDIM, ws+OFF_VDIM, flg);
  k_spatial<<<512,128,0,stream>>>(ws+OFF_QDIM, ws+OFF_QMIX, qs_dw, qs_pw, qs_g, flg);
  // Fourier branch (k)
  k_fft_row<<<8192,128,0,stream>>>(ws+OFF_KDIM, FA, FB);
  k_fft_col<<<4160,128,0,stream>>>(FA, FB, FC, FD);
  k_four_pw<<<130,256,0,stream>>>(FC, FD, FA, FB, FE, al_pw, ah_pw, ph_pw, ph_s, flg);
  k_four_dw<<<2080,256,0,stream>>>(FA, FB, FE, FC, FD, al_dw, ah_dw, flg);
  k_ifft_col<<<4160,128,0,stream>>>(FC, FD, FA, FB);
  k_ifft_row<<<8192,128,0,stream>>>(FA, FB, ws+OFF_KMIX);
  // Wavelet branch (v)
  k_haar<<<64,256,0,stream>>>(ws+OFF_VDIM, Y64, N48, bn_g, bn_b, flg);
  k_wmlp_in<<<6144,256,0,stream>>>(N48, M96, mlp_in, flg);
  k_wmlp_dw<<<6144,256,0,stream>>>(M96, G96, mlp_dw, flg);
  k_wmlp_out<<<3072,256,0,stream>>>(G96, Y64, ws+OFF_VMIX, mlp_out, res_s, flg);
  // Attention (collapsed to Gram matrices)
  k_gram<<<32,256,0,stream>>>(ws+OFF_QMIX, ws+OFF_KMIX, ws+OFF_G);
  k_attn<<<32,256,0,stream>>>(ws+OFF_G, ws+OFF_MB, We, Wproj, rescale, flg);
  k_out<<<16384,256,0,stream>>>(ws+OFF_VMIX, ws+OFF_MB, bproj, d_out, flg);
}